// Round 4
// baseline (3582.991 us; speedup 1.0000x reference)
//
#include <hip/hip_runtime.h>
#include <cstdint>
#include <cstddef>

// Problem dims
#define VV  32000
#define DD  1024
#define HH  1024
#define LL  2
#define BB  64
#define SS  256
#define G4  4096   // 4*H

typedef __attribute__((ext_vector_type(8))) short short8;
typedef __attribute__((ext_vector_type(4))) float f32x4;
typedef __attribute__((ext_vector_type(2))) unsigned int u32x2;
typedef unsigned short u16;
typedef unsigned int u32;

__device__ __forceinline__ u16 f2bf(float f) {
  union { float f; u32 u; } v; v.f = f;
  u32 u = v.u + 0x7fffu + ((v.u >> 16) & 1u);   // RNE
  return (u16)(u >> 16);
}
__device__ __forceinline__ float bf2f(u16 b) {
  union { u32 u; float f; } v; v.u = ((u32)b) << 16;
  return v.f;
}
__device__ __forceinline__ float sigm(float x) { return 1.f / (1.f + __expf(-x)); }
__device__ __forceinline__ float tanh_fast(float x) {
  return 1.f - 2.f / (__expf(2.f * x) + 1.f);   // NaN-free
}

// ---------------------------------------------------------------- embed
__global__ void embed_kernel(const int* __restrict__ inputs,
                             const float* __restrict__ emb,
                             u16* __restrict__ x0) {
  int m = blockIdx.x;              // 0..16383, m = s*64 + b
  int s = m >> 6, b = m & 63;
  int tok = inputs[b * SS + s];
  const f32x4* src = (const f32x4*)(emb + (size_t)tok * DD);
  f32x4 v = src[threadIdx.x];
  u32 lo = (u32)f2bf(v[0]) | ((u32)f2bf(v[1]) << 16);
  u32 hi = (u32)f2bf(v[2]) | ((u32)f2bf(v[3]) << 16);
  u32* dst = (u32*)(x0 + (size_t)m * DD + threadIdx.x * 4);
  dst[0] = lo; dst[1] = hi;
}

// ---------------------------------------------------------------- weight permute
// W_PT[p][k] = bf16(W[k][n]),  n = g*1024+h,  p = h*4+g
__global__ void permW_kernel(const float* __restrict__ Wx, const float* __restrict__ Wh,
                             u16* __restrict__ WxPT, u16* __restrict__ WhPT) {
  __shared__ float tl[64][65];
  int bid = blockIdx.x;
  int which = bid >> 10;           // 0,1: Wx l0/l1 ; 2,3: Wh l0/l1
  int tile = bid & 1023;
  int ktile = tile >> 6, ntile = tile & 63;
  const float* src = ((which < 2) ? Wx : Wh) + (size_t)(which & 1) * G4 * 1024;
  u16* dst = ((which < 2) ? WxPT : WhPT) + (size_t)(which & 1) * G4 * 1024;
  int tid = threadIdx.x;
  #pragma unroll
  for (int i = 0; i < 16; ++i) {
    int idx = i * 256 + tid;
    int kk = idx >> 6, nn = idx & 63;
    tl[kk][nn] = src[(size_t)(ktile * 64 + kk) * G4 + ntile * 64 + nn];
  }
  __syncthreads();
  #pragma unroll
  for (int i = 0; i < 16; ++i) {
    int idx = i * 256 + tid;
    int nn = idx >> 6, kk = idx & 63;
    int n = ntile * 64 + nn;
    int p = ((n & 1023) << 2) | (n >> 10);
    dst[(size_t)p * 1024 + ktile * 64 + kk] = f2bf(tl[kk][nn]);
  }
}

__global__ void permB_kernel(const float* __restrict__ bb, float* __restrict__ bP) {
  int idx = blockIdx.x * 256 + threadIdx.x;  // 8192
  int l = idx >> 12, p = idx & 4095;
  int h = p >> 2, g = p & 3;
  bP[idx] = bb[l * G4 + g * 1024 + h];
}

// ---------------------------------------------------------------- xg GEMM (m97 structure)
__device__ __forceinline__ void gld_lds16(const void* g, void* l) {
  __builtin_amdgcn_global_load_lds((const __attribute__((address_space(1))) unsigned int*)g,
                                   (__attribute__((address_space(3))) unsigned int*)l, 16, 0, 0);
}

__global__ __launch_bounds__(256) void gemm_xg(
    const u16* __restrict__ A, const u16* __restrict__ W,
    const float* __restrict__ bP, float* Cf, u16* Cb, int out_f32) {
  __shared__ u16 As[128 * 32];
  __shared__ u16 Bs[128 * 32];
  const int tid = threadIdx.x;
  const int wave = tid >> 6, lane = tid & 63;
  const int bid = blockIdx.x;
  const int nt = bid & 31, mt = bid >> 5;
  const u16* Ap = A + (size_t)mt * 128 * 1024;
  const u16* Wp = W + (size_t)nt * 128 * 1024;
  f32x4 acc[4][4];
  #pragma unroll
  for (int i = 0; i < 4; ++i)
    #pragma unroll
    for (int j = 0; j < 4; ++j) acc[i][j] = (f32x4){0.f, 0.f, 0.f, 0.f};
  const int wm = wave >> 1, wn = wave & 1;
  const int r16 = lane & 15, oct = lane >> 4;
  for (int k0 = 0; k0 < 1024; k0 += 32) {
    #pragma unroll
    for (int issue = 0; issue < 2; ++issue) {
      int cb = issue * 256 + wave * 64;
      int c = cb + lane;
      gld_lds16(Ap + (size_t)(c >> 2) * 1024 + k0 + (c & 3) * 8, As + (size_t)cb * 8);
      gld_lds16(Wp + (size_t)(c >> 2) * 1024 + k0 + (c & 3) * 8, Bs + (size_t)cb * 8);
    }
    asm volatile("s_waitcnt vmcnt(0)" ::: "memory");
    __syncthreads();
    short8 af[4], bfr[4];
    #pragma unroll
    for (int i = 0; i < 4; ++i)
      af[i] = *(const short8*)(As + (wm * 64 + i * 16 + r16) * 32 + oct * 8);
    #pragma unroll
    for (int j = 0; j < 4; ++j)
      bfr[j] = *(const short8*)(Bs + (wn * 64 + j * 16 + r16) * 32 + oct * 8);
    #pragma unroll
    for (int i = 0; i < 4; ++i)
      #pragma unroll
      for (int j = 0; j < 4; ++j)
        acc[i][j] = __builtin_amdgcn_mfma_f32_16x16x32_bf16(af[i], bfr[j], acc[i][j], 0, 0, 0);
    __syncthreads();
  }
  #pragma unroll
  for (int j = 0; j < 4; ++j) {
    int n = nt * 128 + wn * 64 + j * 16 + r16;
    float bias = bP[n];
    #pragma unroll
    for (int i = 0; i < 4; ++i) {
      int m = mt * 128 + wm * 64 + i * 16 + oct * 4;
      #pragma unroll
      for (int r = 0; r < 4; ++r) {
        float val = acc[i][j][r] + bias;
        if (out_f32) Cf[(size_t)(m + r) * G4 + n] = val;
        else         Cb[(size_t)(m + r) * G4 + n] = f2bf(val);
      }
    }
  }
}

// ---------------------------------------------------------------- persistent LSTM recurrence
// grid 256 = 4 batch-groups x 64 col-groups; block 256 thr (4 waves).
// Waves split K (256 each); all 64 p-cols per wave; B in 128 AGPRs.
// A-fragments loaded per-lane directly from LLC (sc1) - NO LDS h tile.
// Manual s_waitcnt/s_barrier discipline keeps xg prefetch in flight.
__global__ __launch_bounds__(256, 1) void recur_kernel(
    const u16* __restrict__ WhPT,   // [4096][1024] this layer
    const float* xgf, const u16* xgb, int xg_f32,   // [16384][4096] (m = t*64+b)
    const int* __restrict__ lengths,
    u16* __restrict__ hbuf_l,       // [2][64][1024] bf16 this layer (pre-zeroed)
    u16* __restrict__ hs_out,       // layer0: [16384][1024] bf16
    float* __restrict__ x_out,      // layer1: [64][256][1024] f32
    float* __restrict__ c_out, float* __restrict__ h_out,  // [64][1024] f32
    int layer, int* flags_l) {      // flags_l[4][64] this layer (pre-zeroed)
  __shared__ alignas(16) float gbuf[4][16][68];   // [wave][batch][p], pad 68: 2-way banks
  __shared__ int len_s[16];
  const int tid = threadIdx.x;
  const int wave = tid >> 6, lane = tid & 63;
  const int bg = blockIdx.x >> 6, cg = blockIdx.x & 63;
  const int r16 = lane & 15, oct = lane >> 4;

  // B-frags: bfrag[nt*8+ks] = WhPT[cg*64+nt*16+r16][wave*256+ks*32+oct*8 ..+8], AGPR-pinned
  short8 bfrag[32];
  {
    const u16* wbase = WhPT + (size_t)(cg * 64 + r16) * 1024 + wave * 256 + oct * 8;
    #pragma unroll
    for (int ntl = 0; ntl < 4; ++ntl)
      #pragma unroll
      for (int ks = 0; ks < 8; ++ks)
        bfrag[ntl * 8 + ks] = *(const short8*)(wbase + (size_t)ntl * 16 * 1024 + ks * 32);
    #pragma unroll
    for (int kk = 0; kk < 32; ++kk) asm volatile("" : "+a"(bfrag[kk]));
  }
  if (tid < 16) len_s[tid] = lengths[bg * 16 + tid];
  const int b_loc = tid >> 4, hc_loc = tid & 15;
  const int b_glob = bg * 16 + b_loc;
  const int hc_glob = cg * 16 + hc_loc;
  float c_reg = 0.f, h_reg = 0.f;
  int* myflags = flags_l + bg * 64;

  // per-wave A base (row = batch r16, k = wave*256 + oct*8)
  const u16* hrow = hbuf_l + (size_t)(bg * 16 + r16) * 1024 + wave * 256 + oct * 8;
  // per-thread xg base (4 gates of (b_glob, hc_glob) are contiguous: p = hc*4+g)
  const float* xg_tb_f = xgf + (size_t)b_glob * G4 + (size_t)hc_glob * 4;
  const u16*   xg_tb_b = xgb + (size_t)b_glob * G4 + (size_t)hc_glob * 4;

  // preload xg[0]
  f32x4 xg_cur_f = (f32x4){0.f,0.f,0.f,0.f};
  u32x2 xg_cur_b = (u32x2){0u,0u};
  if (xg_f32) xg_cur_f = *(const f32x4*)(xg_tb_f);
  else        xg_cur_b = *(const u32x2*)(xg_tb_b);
  asm volatile("s_waitcnt vmcnt(0) lgkmcnt(0)" ::: "memory");
  __builtin_amdgcn_s_barrier();       // clean state: 0 outstanding vmem per wave

  for (int t = 0; t < SS; ++t) {
    // ---- P8: poll peer flags >= t (all waves independently; lane l watches block l)
    while (true) {
      int f = __hip_atomic_load(&myflags[lane], __ATOMIC_RELAXED, __HIP_MEMORY_SCOPE_AGENT);
      if (__ballot(f < t) == 0ull) break;
      __builtin_amdgcn_s_sleep(1);
    }
    // ---- P9: issue 8 A-loads (sc1, LLC) + xg[t+1] prefetch; wait A only (vmcnt(1))
    unsigned long long ha = (unsigned long long)(hrow + (size_t)(t & 1) * (BB * 1024));
    int tn = (t + 1 < SS) ? (t + 1) : (SS - 1);
    short8 a0, a1, a2, a3, a4, a5, a6, a7;
    f32x4 xg_nxt_f; u32x2 xg_nxt_b;
    if (xg_f32) {
      unsigned long long xga = (unsigned long long)(xg_tb_f + (size_t)tn * (64 * G4));
      asm volatile(
        "global_load_dwordx4 %0, %9, off sc1\n\t"
        "global_load_dwordx4 %1, %9, off offset:64 sc1\n\t"
        "global_load_dwordx4 %2, %9, off offset:128 sc1\n\t"
        "global_load_dwordx4 %3, %9, off offset:192 sc1\n\t"
        "global_load_dwordx4 %4, %9, off offset:256 sc1\n\t"
        "global_load_dwordx4 %5, %9, off offset:320 sc1\n\t"
        "global_load_dwordx4 %6, %9, off offset:384 sc1\n\t"
        "global_load_dwordx4 %7, %9, off offset:448 sc1\n\t"
        "global_load_dwordx4 %8, %10, off\n\t"
        "s_waitcnt vmcnt(1)"
        : "=v"(a0), "=v"(a1), "=v"(a2), "=v"(a3),
          "=v"(a4), "=v"(a5), "=v"(a6), "=v"(a7), "=v"(xg_nxt_f)
        : "v"(ha), "v"(xga) : "memory");
    } else {
      unsigned long long xga = (unsigned long long)(xg_tb_b + (size_t)tn * (64 * G4));
      asm volatile(
        "global_load_dwordx4 %0, %9, off sc1\n\t"
        "global_load_dwordx4 %1, %9, off offset:64 sc1\n\t"
        "global_load_dwordx4 %2, %9, off offset:128 sc1\n\t"
        "global_load_dwordx4 %3, %9, off offset:192 sc1\n\t"
        "global_load_dwordx4 %4, %9, off offset:256 sc1\n\t"
        "global_load_dwordx4 %5, %9, off offset:320 sc1\n\t"
        "global_load_dwordx4 %6, %9, off offset:384 sc1\n\t"
        "global_load_dwordx4 %7, %9, off offset:448 sc1\n\t"
        "global_load_dwordx2 %8, %10, off\n\t"
        "s_waitcnt vmcnt(1)"
        : "=v"(a0), "=v"(a1), "=v"(a2), "=v"(a3),
          "=v"(a4), "=v"(a5), "=v"(a6), "=v"(a7), "=v"(xg_nxt_b)
        : "v"(ha), "v"(xga) : "memory");
    }
    // ---- P10: MFMA, K=256 per wave, 4 N-tiles
    f32x4 acc[4];
    #pragma unroll
    for (int n = 0; n < 4; ++n) acc[n] = (f32x4){0.f, 0.f, 0.f, 0.f};
    short8 af[8] = {a0, a1, a2, a3, a4, a5, a6, a7};
    #pragma unroll
    for (int ks = 0; ks < 8; ++ks)
      #pragma unroll
      for (int n = 0; n < 4; ++n)
        acc[n] = __builtin_amdgcn_mfma_f32_16x16x32_bf16(af[ks], bfrag[n * 8 + ks], acc[n], 0, 0, 0);
    // ---- P1: write partials to LDS  gbuf[wave][batch=oct*4+r][p=n*16+r16]
    #pragma unroll
    for (int n = 0; n < 4; ++n)
      #pragma unroll
      for (int r = 0; r < 4; ++r)
        gbuf[wave][oct * 4 + r][n * 16 + r16] = acc[n][r];
    // ---- P2: barrier (LDS-only wait; xg load stays in flight)
    asm volatile("s_waitcnt lgkmcnt(0)\n\ts_barrier" ::: "memory");
    // ---- P3: reduce 4 wave-partials + LSTM cell; thread owns (b_loc, hc_loc)
    f32x4 g0 = *(const f32x4*)(&gbuf[0][b_loc][hc_loc * 4]);
    f32x4 g1 = *(const f32x4*)(&gbuf[1][b_loc][hc_loc * 4]);
    f32x4 g2 = *(const f32x4*)(&gbuf[2][b_loc][hc_loc * 4]);
    f32x4 g3 = *(const f32x4*)(&gbuf[3][b_loc][hc_loc * 4]);
    f32x4 gs = (g0 + g1) + (g2 + g3);
    f32x4 xv;
    if (xg_f32) xv = xg_cur_f;
    else {
      xv[0] = bf2f((u16)(xg_cur_b[0] & 0xffff)); xv[1] = bf2f((u16)(xg_cur_b[0] >> 16));
      xv[2] = bf2f((u16)(xg_cur_b[1] & 0xffff)); xv[3] = bf2f((u16)(xg_cur_b[1] >> 16));
    }
    float si = sigm(gs[0] + xv[0]);
    float sf = sigm(gs[1] + xv[1]);
    float gg = tanh_fast(gs[2] + xv[2]);
    float so = sigm(gs[3] + xv[3]);
    float c_new = sf * c_reg + si * gg;
    float h_new = so * tanh_fast(c_new);
    if (t < len_s[b_loc]) { c_reg = c_new; h_reg = h_new; }
    // ---- P4: publish h[t+1] (packed u32, even threads, agent-coherent)
    u32 hb = (u32)f2bf(h_reg);
    u32 nb = (u32)__shfl_xor((int)hb, 1);
    u32 packed = hb | (nb << 16);
    if (!(tid & 1))
      __hip_atomic_store((u32*)(hbuf_l + (size_t)((t + 1) & 1) * (BB * 1024) +
                                (size_t)b_glob * 1024 + hc_glob),
                         packed, __ATOMIC_RELAXED, __HIP_MEMORY_SCOPE_AGENT);
    // ---- P5: release - h store (and stray) acked at LLC
    asm volatile("s_waitcnt vmcnt(0)" ::: "memory");
    // ---- P5.5: all waves of this block released
    asm volatile("s_barrier" ::: "memory");
    // ---- P6: flag
    if (tid == 0)
      __hip_atomic_store(&myflags[cg], t + 1, __ATOMIC_RELAXED, __HIP_MEMORY_SCOPE_AGENT);
    // ---- P7: outputs (fire-and-forget, hidden under next poll)
    if (layer == 0) {
      if (!(tid & 1))
        __builtin_nontemporal_store(packed,
            (u32*)(hs_out + (size_t)(t * 64 + b_glob) * 1024 + hc_glob));
    } else {
      __builtin_nontemporal_store(h_reg,
          x_out + (size_t)(b_glob * SS + t) * 1024 + hc_glob);
    }
    xg_cur_f = xg_nxt_f;
    xg_cur_b = xg_nxt_b;
  }
  c_out[(size_t)b_glob * 1024 + hc_glob] = c_reg;
  h_out[(size_t)b_glob * 1024 + hc_glob] = h_reg;
}

// ---------------------------------------------------------------- launch
extern "C" void kernel_launch(void* const* d_in, const int* in_sizes, int n_in,
                              void* d_out, int out_size, void* d_ws, size_t ws_size,
                              hipStream_t stream) {
  const int* inputs  = (const int*)d_in[0];
  const int* lengths = (const int*)d_in[1];
  const float* emb   = (const float*)d_in[3];
  const float* Wx    = (const float*)d_in[4];
  const float* Wh    = (const float*)d_in[5];
  const float* bb    = (const float*)d_in[6];
  float* out = (float*)d_out;

  char* ws = (char*)d_ws;
  size_t off = 0;
  auto alloc = [&](size_t bytes) -> void* {
    void* p = ws + off;
    off = (off + bytes + 255) & ~(size_t)255;
    return p;
  };
  u16* WxPT = (u16*)alloc((size_t)2 * G4 * 1024 * 2);
  u16* WhPT = (u16*)alloc((size_t)2 * G4 * 1024 * 2);
  float* bP = (float*)alloc((size_t)2 * G4 * 4);
  u16* x0   = (u16*)alloc((size_t)16384 * 1024 * 2);
  u16* hs0  = (u16*)alloc((size_t)16384 * 1024 * 2);
  u16* hbuf = (u16*)alloc((size_t)2 * 2 * BB * 1024 * 2);  // [layer][2][64][1024]
  int* flags = (int*)alloc(2048);          // [2 layers][4 groups][64 blocks]
  size_t xg_f32_bytes = (size_t)16384 * G4 * 4;
  int xg_f32 = (ws_size > off) && ((ws_size - off) >= xg_f32_bytes);
  float* xgf = (float*)(ws + off);
  u16* xgb   = (u16*)(ws + off);

  hipMemsetAsync(flags, 0, 2048, stream);
  hipMemsetAsync(hbuf, 0, (size_t)2 * 2 * BB * 1024 * 2, stream);
  embed_kernel<<<dim3(16384), dim3(256), 0, stream>>>(inputs, emb, x0);
  permW_kernel<<<dim3(4096), dim3(256), 0, stream>>>(Wx, Wh, WxPT, WhPT);
  permB_kernel<<<dim3(32), dim3(256), 0, stream>>>(bb, bP);

  float* cs_base = out + (size_t)BB * SS * HH;
  float* hs_base = cs_base + (size_t)LL * BB * HH;

  for (int layer = 0; layer < 2; ++layer) {
    const u16* Aten = (layer == 0) ? x0 : hs0;
    gemm_xg<<<dim3(4096), dim3(256), 0, stream>>>(
        Aten, WxPT + (size_t)layer * G4 * 1024, bP + layer * G4, xgf, xgb, xg_f32);
    const u16* Whl = WhPT + (size_t)layer * G4 * 1024;
    u16* hbuf_l = hbuf + (size_t)layer * 2 * BB * 1024;
    float* c_out_p = cs_base + (size_t)layer * BB * HH;
    float* h_out_p = hs_base + (size_t)layer * BB * HH;
    int* flags_l = flags + layer * 256;
    const float* xgf_c = xgf; const u16* xgb_c = xgb;
    void* args[] = { (void*)&Whl, (void*)&xgf_c, (void*)&xgb_c, (void*)&xg_f32,
                     (void*)&lengths, (void*)&hbuf_l, (void*)&hs0, (void*)&out,
                     (void*)&c_out_p, (void*)&h_out_p, (void*)&layer,
                     (void*)&flags_l };
    hipLaunchCooperativeKernel((void*)recur_kernel, dim3(256), dim3(256), args, 0, stream);
  }
}